// Round 2
// baseline (1548.555 us; speedup 1.0000x reference)
//
#include <hip/hip_runtime.h>
#include <hip/hip_bf16.h>

#define B_ 256
#define D_ 512
#define E_ 512
#define K_ 154

typedef __attribute__((ext_vector_type(8))) short short8;
typedef __attribute__((ext_vector_type(4))) float f32x4;

#define AS1 __attribute__((address_space(1)))
#define AS3 __attribute__((address_space(3)))

__device__ __forceinline__ unsigned short f2bf(float f) {
    unsigned u = __float_as_uint(f);
    u = (u + 0x7fffu + ((u >> 16) & 1u)) >> 16;
    return (unsigned short)u;
}

// RNE pack of two f32 -> one u32 holding 2x bf16 (low = a, high = b).
__device__ __forceinline__ unsigned cvt_pk_bf16(float a, float b) {
    unsigned r;
    asm("v_cvt_pk_bf16_f32 %0, %1, %2" : "=v"(r) : "v"(a), "v"(b));
    return r;
}

__device__ __forceinline__ short8 pack_bf16x8(f32x4 a, f32x4 b) {
    union { unsigned u[4]; short8 s; } r;
    r.u[0] = cvt_pk_bf16(a.x, a.y);
    r.u[1] = cvt_pk_bf16(a.z, a.w);
    r.u[2] = cvt_pk_bf16(b.x, b.y);
    r.u[3] = cvt_pk_bf16(b.z, b.w);
    return r.s;
}

// ---------------- kernel 1: gate logits, fp64, LDS-tiled & coalesced -------
__global__ __launch_bounds__(512) void k_gate(const float* __restrict__ x,
                                              const float* __restrict__ gw,
                                              double* __restrict__ logits) {
    const int tg = blockIdx.x;   // 0..31 : 8 tokens
    const int eg = blockIdx.y;   // 0..7  : 64 experts
    const int tid = threadIdx.x;
    const int t0 = tg * 8, e0 = eg * 64;
    __shared__ double xs[8][512];     // 32 KB
    __shared__ float gws[64][65];     // 16.6 KB, +1 pad
    #pragma unroll
    for (int i = 0; i < 8; ++i) {
        int j = i * 512 + tid;
        xs[j >> 9][j & 511] = (double)x[(t0 + (j >> 9)) * D_ + (j & 511)];
    }
    const int e = tid & 63, tl = tid >> 6;
    double acc = 0.0;
    for (int dc = 0; dc < 8; ++dc) {
        __syncthreads();
        #pragma unroll
        for (int i = 0; i < 8; ++i) {
            int j = i * 512 + tid;
            gws[j >> 6][j & 63] = gw[(e0 + (j >> 6)) * D_ + dc * 64 + (j & 63)];
        }
        __syncthreads();
        #pragma unroll 8
        for (int d = 0; d < 64; ++d)
            acc = fma((double)gws[e][d], xs[tl][dc * 64 + d], acc);
    }
    logits[(t0 + tl) * E_ + e0 + e] = acc;
}

// ---------------- kernel 2: exact top-k (rank) + fp64 softmax + x->bf16 ----
__global__ __launch_bounds__(512) void k_topk(const double* __restrict__ logits,
                                              const float* __restrict__ gb,
                                              const float* __restrict__ x,
                                              float* __restrict__ wT,
                                              unsigned short* __restrict__ xb) {
    const int b = blockIdx.x;
    const int e = threadIdx.x;
    __shared__ double vals[E_];
    __shared__ double red[512];
    double v = logits[b * E_ + e] + (double)gb[e];
    vals[e] = v;
    xb[b * D_ + e] = f2bf(x[b * D_ + e]);   // D_ == E_ == 512
    __syncthreads();
    int cnt = 0;
    double m = -1.0e300;
    for (int j = 0; j < E_; ++j) {
        double vj = vals[j];
        m = fmax(m, vj);
        cnt += (vj > v || (vj == v && j < e)) ? 1 : 0;
    }
    double p = (cnt < K_) ? exp(v - m) : 0.0;
    red[e] = p;
    __syncthreads();
    for (int s = 256; s > 0; s >>= 1) {
        if (e < s) red[e] += red[e + s];
        __syncthreads();
    }
    wT[e * B_ + b] = (float)(p / red[0]);
}

// ---------------- kernel 3: main contraction, async gload_lds pipeline -----
// grid = 16 n-tiles(32) x (512/EPG) expert-groups; block 256 (4 waves).
// v3: global_load_lds width=16 double-buffered 2-phase pipeline (guide §5
// step 3). Each instr keeps 1 KB in flight with no VGPR cost -> HBM stream
// saturates independent of occupancy (v2's failure: 870 GB/s latency-bound,
// only ~1 KB/CU in flight via register loads).
// Swizzle (rule #21, both-sides): LDS layout [row][chunk16] is written
// linearly by the DMA; the GLOBAL source address is pre-permuted per lane
// with a 32B-unit XOR (unit ^= row&7), and ds_read applies the same
// involution. Rows at 256B stride would otherwise be a 16-way bank
// conflict; this reduces to ~4-way (free-ish, hidden under HBM stream).
// Step = (kc, p): stages 4 experts x [32 n x 64 k] fp32 = 32 KB / buffer.
// LDS: 64 KB (2 buf) + EPG KB ws -> 80 KB @EPG=16 -> 2 blocks/CU.
template <int EPG, bool TWO>
__global__ __launch_bounds__(256, 2) void k_moe(const unsigned short* __restrict__ xb,
                                                const float* __restrict__ wT,
                                                const float* __restrict__ tiles,
                                                float* __restrict__ dst) {
    const int nt = blockIdx.x & 15;
    const int g  = blockIdx.x >> 4;
    const int n0 = nt * 32;
    const int e0 = g * EPG;
    const int tid  = threadIdx.x;
    const int wv   = tid >> 6;
    const int lane = tid & 63;
    const int m0   = wv * 64;
    const int quad = lane >> 4;
    const int l16  = lane & 15;
    constexpr int PSTEPS = EPG / 4;
    constexpr int NSTEP  = 8 * PSTEPS;

    __shared__ __align__(16) float Bs[2][4][32][64];   // 64 KB, fp32 staged
    __shared__ float ws[EPG][B_];                      // EPG KB

    #pragma unroll
    for (int i = 0; i < EPG; ++i) {
        int idx = i * 256 + tid;
        ws[idx >> 8][idx & 255] = wT[(e0 + (idx >> 8)) * B_ + (idx & 255)];
    }

    // stage one step: wave wv stages expert (p*4 + wv), rows n0..n0+31,
    // k-slab kc*64..+64. 8 instrs x 1 KB. Source pre-swizzled so that the
    // linear DMA write lands data at phys chunk = logical chunk XOR'd.
    const int rl = lane >> 4;    // row-in-group 0..3
    const int pc = lane & 15;    // physical 16B chunk within row
    auto stage = [&](int buf, int step) {
        const int kc = step / PSTEPS, p = step % PSTEPS;
        const int eg = e0 + p * 4 + wv;
        const float* rowbase = tiles + ((size_t)eg * D_ + n0) * D_ + kc * 64;
        float* dbase = &Bs[buf][wv][0][0];
        #pragma unroll
        for (int i = 0; i < 8; ++i) {
            const int r = i * 4 + rl;
            const int c = ((((pc >> 1) ^ (r & 7)) << 1) | (pc & 1));  // logical chunk
            const float* src = rowbase + (size_t)r * D_ + c * 4;
            __builtin_amdgcn_global_load_lds((const AS1 void*)src,
                                             (AS3 void*)(dbase + i * 256),
                                             16, 0, 0);
        }
    };

    f32x4 Ct[4][2];
    #pragma unroll
    for (int mi = 0; mi < 4; ++mi)
        #pragma unroll
        for (int ni = 0; ni < 2; ++ni)
            Ct[mi][ni] = (f32x4){0.f, 0.f, 0.f, 0.f};

    stage(0, 0);
    __syncthreads();   // covers ws writes + prologue stage drain
    int cur = 0;

    for (int kc = 0; kc < 8; ++kc) {
        const int k0 = kc * 64;
        // A fragments from xb (bf16, L2-resident): once per kc
        short8 A[4][2];
        #pragma unroll
        for (int mi = 0; mi < 4; ++mi)
            #pragma unroll
            for (int ks = 0; ks < 2; ++ks)
                A[mi][ks] = *(const short8*)&xb[(m0 + mi * 16 + l16) * D_ + k0 + ks * 32 + quad * 8];

        #pragma unroll
        for (int p = 0; p < PSTEPS; ++p) {
            const int step = kc * PSTEPS + p;
            if (step + 1 < NSTEP) stage(cur ^ 1, step + 1);   // issue next loads

            #pragma unroll
            for (int el = 0; el < 4; ++el) {
                const float* bsrc = &Bs[cur][el][0][0];
                f32x4 Ce[4][2];
                #pragma unroll
                for (int mi = 0; mi < 4; ++mi)
                    #pragma unroll
                    for (int ni = 0; ni < 2; ++ni)
                        Ce[mi][ni] = (f32x4){0.f, 0.f, 0.f, 0.f};
                #pragma unroll
                for (int ks = 0; ks < 2; ++ks) {
                    short8 Bf[2];
                    #pragma unroll
                    for (int ni = 0; ni < 2; ++ni) {
                        const int r  = ni * 16 + l16;
                        const int ph = (((ks * 4 + quad) ^ (r & 7)) << 1);  // phys chunk
                        const float* q = bsrc + r * 64 + ph * 4;
                        f32x4 u = *(const f32x4*)q;
                        f32x4 v = *(const f32x4*)(q + 4);
                        Bf[ni] = pack_bf16x8(u, v);
                    }
                    #pragma unroll
                    for (int mi = 0; mi < 4; ++mi)
                        #pragma unroll
                        for (int ni = 0; ni < 2; ++ni)
                            Ce[mi][ni] = __builtin_amdgcn_mfma_f32_16x16x32_bf16(
                                A[mi][ks], Bf[ni], Ce[mi][ni], 0, 0, 0);
                }
                // C/D layout: col = l16 (n), row = quad*4 + reg
                const float* wrow = ws[p * 4 + el];
                #pragma unroll
                for (int mi = 0; mi < 4; ++mi) {
                    const int rbase = m0 + mi * 16 + quad * 4;
                    float w0 = wrow[rbase + 0], w1 = wrow[rbase + 1];
                    float w2 = wrow[rbase + 2], w3 = wrow[rbase + 3];
                    #pragma unroll
                    for (int ni = 0; ni < 2; ++ni) {
                        Ct[mi][ni].x += w0 * Ce[mi][ni].x;
                        Ct[mi][ni].y += w1 * Ce[mi][ni].y;
                        Ct[mi][ni].z += w2 * Ce[mi][ni].z;
                        Ct[mi][ni].w += w3 * Ce[mi][ni].w;
                    }
                }
            }
            __syncthreads();   // drains this step's stage (compiler vmcnt(0))
            cur ^= 1;          // and fences buf reuse
        }
    }

    #pragma unroll
    for (int mi = 0; mi < 4; ++mi)
        #pragma unroll
        for (int ni = 0; ni < 2; ++ni) {
            const int row = m0 + mi * 16 + quad * 4;
            const int col = n0 + ni * 16 + l16;
            if (TWO) {
                float* base = dst + ((size_t)g * B_ + row) * D_ + col;
                __builtin_nontemporal_store(Ct[mi][ni].x, base + 0 * D_);
                __builtin_nontemporal_store(Ct[mi][ni].y, base + 1 * D_);
                __builtin_nontemporal_store(Ct[mi][ni].z, base + 2 * D_);
                __builtin_nontemporal_store(Ct[mi][ni].w, base + 3 * D_);
            } else {
                unsafeAtomicAdd(&dst[(row + 0) * D_ + col], Ct[mi][ni].x);
                unsafeAtomicAdd(&dst[(row + 1) * D_ + col], Ct[mi][ni].y);
                unsafeAtomicAdd(&dst[(row + 2) * D_ + col], Ct[mi][ni].z);
                unsafeAtomicAdd(&dst[(row + 3) * D_ + col], Ct[mi][ni].w);
            }
        }
}

// ---------------- kernel 4: sum the NG partial copies -----------------------
template <int NG>
__global__ __launch_bounds__(256) void k_reduce(const float* __restrict__ P,
                                                float* __restrict__ out) {
    const int t = blockIdx.x * 256 + threadIdx.x;   // 0..32767 (float4 idx)
    const f32x4* p4 = (const f32x4*)P;
    f32x4 acc = (f32x4){0.f, 0.f, 0.f, 0.f};
    #pragma unroll 8
    for (int gidx = 0; gidx < NG; ++gidx) {
        f32x4 v = __builtin_nontemporal_load(p4 + (size_t)gidx * 32768 + t);
        acc.x += v.x; acc.y += v.y; acc.z += v.z; acc.w += v.w;
    }
    ((f32x4*)out)[t] = acc;
}

extern "C" void kernel_launch(void* const* d_in, const int* in_sizes, int n_in,
                              void* d_out, int out_size, void* d_ws, size_t ws_size,
                              hipStream_t stream) {
    const float* x     = (const float*)d_in[0];
    const float* gw    = (const float*)d_in[1];
    const float* gb    = (const float*)d_in[2];
    const float* tiles = (const float*)d_in[3];
    float* out = (float*)d_out;

    // ws layout: xb bf16 (256 KB) | wT f32 (512 KB) | { logits f64 (1 MB) / P }
    // P aliases logits: logits are dead once k_topk finishes.
    char* base = (char*)d_ws;
    unsigned short* xb  = (unsigned short*)base;
    float* wT           = (float*)(base + 262144);
    double* logits      = (double*)(base + 262144 + 524288);
    float* P            = (float*)(base + 262144 + 524288);
    const size_t fixed  = 262144 + 524288;                       // xb + wT
    const size_t slot   = (size_t)B_ * D_ * sizeof(float);       // 512 KB
    const size_t need16 = fixed + 32 * slot;                     // ~16.75 MiB
    const size_t need32 = fixed + 16 * slot;                     // ~8.75 MiB

    k_gate<<<dim3(32, 8), 512, 0, stream>>>(x, gw, logits);
    k_topk<<<256, 512, 0, stream>>>(logits, gb, x, wT, xb);
    if (ws_size >= need16) {
        k_moe<16, true><<<512, 256, 0, stream>>>(xb, wT, tiles, P);
        k_reduce<32><<<128, 256, 0, stream>>>(P, out);
    } else if (ws_size >= need32) {
        k_moe<32, true><<<256, 256, 0, stream>>>(xb, wT, tiles, P);
        k_reduce<16><<<128, 256, 0, stream>>>(P, out);
    } else {
        hipMemsetAsync(out, 0, (size_t)out_size * sizeof(float), stream);
        k_moe<8, false><<<1024, 256, 0, stream>>>(xb, wT, tiles, out);
    }
}

// Round 3
// 1102.602 us; speedup vs baseline: 1.4045x; 1.4045x over previous
//
#include <hip/hip_runtime.h>
#include <hip/hip_bf16.h>

#define B_ 256
#define D_ 512
#define E_ 512
#define K_ 154

typedef __attribute__((ext_vector_type(8))) short short8;
typedef __attribute__((ext_vector_type(4))) float f32x4;

__device__ __forceinline__ unsigned short f2bf(float f) {
    unsigned u = __float_as_uint(f);
    u = (u + 0x7fffu + ((u >> 16) & 1u)) >> 16;
    return (unsigned short)u;
}

// RNE pack of two f32 -> one u32 of 2x bf16 (low = a, high = b). Same bits
// as f2bf (both RNE); single VALU op.
__device__ __forceinline__ unsigned cvt_pk_bf16(float a, float b) {
    unsigned r;
    asm("v_cvt_pk_bf16_f32 %0, %1, %2" : "=v"(r) : "v"(a), "v"(b));
    return r;
}

// ---------------- kernel 1: gate logits, fp64, LDS-tiled & coalesced -------
__global__ __launch_bounds__(512) void k_gate(const float* __restrict__ x,
                                              const float* __restrict__ gw,
                                              double* __restrict__ logits) {
    const int tg = blockIdx.x;   // 0..31 : 8 tokens
    const int eg = blockIdx.y;   // 0..7  : 64 experts
    const int tid = threadIdx.x;
    const int t0 = tg * 8, e0 = eg * 64;
    __shared__ double xs[8][512];     // 32 KB
    __shared__ float gws[64][65];     // 16.6 KB, +1 pad
    #pragma unroll
    for (int i = 0; i < 8; ++i) {
        int j = i * 512 + tid;
        xs[j >> 9][j & 511] = (double)x[(t0 + (j >> 9)) * D_ + (j & 511)];
    }
    const int e = tid & 63, tl = tid >> 6;
    double acc = 0.0;
    for (int dc = 0; dc < 8; ++dc) {
        __syncthreads();
        #pragma unroll
        for (int i = 0; i < 8; ++i) {
            int j = i * 512 + tid;
            gws[j >> 6][j & 63] = gw[(e0 + (j >> 6)) * D_ + dc * 64 + (j & 63)];
        }
        __syncthreads();
        #pragma unroll 8
        for (int d = 0; d < 64; ++d)
            acc = fma((double)gws[e][d], xs[tl][dc * 64 + d], acc);
    }
    logits[(t0 + tl) * E_ + e0 + e] = acc;
}

// ---------------- kernel 2: exact top-k (rank) + fp64 softmax + x->bf16 ----
__global__ __launch_bounds__(512) void k_topk(const double* __restrict__ logits,
                                              const float* __restrict__ gb,
                                              const float* __restrict__ x,
                                              float* __restrict__ wT,
                                              unsigned short* __restrict__ xb) {
    const int b = blockIdx.x;
    const int e = threadIdx.x;
    __shared__ double vals[E_];
    __shared__ double red[512];
    double v = logits[b * E_ + e] + (double)gb[e];
    vals[e] = v;
    xb[b * D_ + e] = f2bf(x[b * D_ + e]);   // D_ == E_ == 512
    __syncthreads();
    int cnt = 0;
    double m = -1.0e300;
    for (int j = 0; j < E_; ++j) {
        double vj = vals[j];
        m = fmax(m, vj);
        cnt += (vj > v || (vj == v && j < e)) ? 1 : 0;
    }
    double p = (cnt < K_) ? exp(v - m) : 0.0;
    red[e] = p;
    __syncthreads();
    for (int s = 256; s > 0; s >>= 1) {
        if (e < s) red[e] += red[e + s];
        __syncthreads();
    }
    wT[e * B_ + b] = (float)(p / red[0]);
}

// ---------------- kernel 3: main contraction, T14 reg-staged pipeline ------
// grid = 16 n-tiles(32) x (512/EPG) expert-groups; block 256 (4 waves).
// v4 = round-0 structure + T14 async-STAGE split + double-buffered Bs:
//   issue step s+1's 8x16B loads into 32 VGPRs BEFORE computing step s from
//   LDS, convert+write them to Bs[cur^1] after, ONE barrier per step.
//   In flight during compute: 128 B/thread x 512 thr/CU = 64 KB/CU.
// v3 post-mortem: global_load_lds + per-lane swizzled src addresses spilled
// (WRITE_SIZE 1.7 GB of scratch). This version's VGPR budget: st 32 + A 32
// + Bf 8 + addr ~32 = ~104 V + 64 acc -> fits a 128/128 V/A split.
// Tiles loaded with PLAIN cached loads: L3 (256 MB) keeps ~half of the
// 537 MB tiles resident across bench iterations (round-1: FETCH 265 MB).
// Bs pad: row stride 72 shorts -> ds_read banks 4r mod 32 = 2-way (free).
template <int EPG, bool TWO>
__global__ __launch_bounds__(256, 2) void k_moe(const unsigned short* __restrict__ xb,
                                                const float* __restrict__ wT,
                                                const float* __restrict__ tiles,
                                                float* __restrict__ dst) {
    const int nt = blockIdx.x & 15;
    const int g  = blockIdx.x >> 4;
    const int n0 = nt * 32;
    const int e0 = g * EPG;
    const int tid  = threadIdx.x;
    const int wv   = tid >> 6;
    const int lane = tid & 63;
    const int m0   = wv * 64;
    const int quad = lane >> 4;
    const int l16  = lane & 15;
    constexpr int PSTEPS = EPG / 4;
    constexpr int NSTEP  = 8 * PSTEPS;

    __shared__ __align__(16) unsigned short Bs[2][4 * 32 * 72];  // 36 KB
    __shared__ float ws[EPG][B_];                                // EPG KB

    // ---- per-thread staging geometry (same coalescing as round-0) ----
    // load i covers expert (i>>1), rows (i&1)*16 + tid>>4, cols (tid&15)*4
    const int srow = tid >> 4;          // 0..15
    const int scol = (tid & 15) * 4;    // 0..60
    // source: float offset from (expert ep, row n0+r, col kc*64+scol)
    //   i-delta: (i>>1)*D_*D_ + (i&1)*16*D_
    // dest (shorts): ((i>>1)*32 + (i&1)*16 + srow)*72 + scol

    #pragma unroll
    for (int i = 0; i < EPG; ++i) {
        int idx = i * 256 + tid;
        ws[idx >> 8][idx & 255] = wT[(e0 + (idx >> 8)) * B_ + (idx & 255)];
    }

    f32x4 Ct[4][2];
    #pragma unroll
    for (int mi = 0; mi < 4; ++mi)
        #pragma unroll
        for (int ni = 0; ni < 2; ++ni)
            Ct[mi][ni] = (f32x4){0.f, 0.f, 0.f, 0.f};

    f32x4 st[8];
    // prologue: load + write step 0 (kc=0, p=0)
    {
        const float* sp = tiles + ((size_t)e0 * D_ + n0 + srow) * D_ + scol;
        #pragma unroll
        for (int i = 0; i < 8; ++i)
            st[i] = *(const f32x4*)(sp + (size_t)(i >> 1) * (D_ * D_) + (i & 1) * (16 * D_));
        #pragma unroll
        for (int i = 0; i < 8; ++i) {
            const int dr = (i >> 1) * 32 + (i & 1) * 16 + srow;
            uint2 v2;
            v2.x = cvt_pk_bf16(st[i].x, st[i].y);
            v2.y = cvt_pk_bf16(st[i].z, st[i].w);
            *(uint2*)&Bs[0][dr * 72 + scol] = v2;
        }
    }
    __syncthreads();   // covers ws + Bs[0]
    int cur = 0;

    for (int kc = 0; kc < 8; ++kc) {
        const int k0 = kc * 64;
        // A fragments from xb (bf16, L2/L3-resident): once per kc
        short8 A[4][2];
        #pragma unroll
        for (int mi = 0; mi < 4; ++mi)
            #pragma unroll
            for (int ks = 0; ks < 2; ++ks)
                A[mi][ks] = *(const short8*)&xb[(m0 + mi * 16 + l16) * D_ + k0 + ks * 32 + quad * 8];

        #pragma unroll 1
        for (int p = 0; p < PSTEPS; ++p) {
            const int s = kc * PSTEPS + p;
            const bool pre = (s + 1 < NSTEP);
            // ---- issue next step's loads (in flight across the compute) ----
            if (pre) {
                const int np  = (p + 1 < PSTEPS) ? p + 1 : 0;
                const int nkc = (p + 1 < PSTEPS) ? kc : kc + 1;
                const float* sp = tiles + ((size_t)(e0 + np * 4) * D_ + n0 + srow) * D_
                                + nkc * 64 + scol;
                #pragma unroll
                for (int i = 0; i < 8; ++i)
                    st[i] = *(const f32x4*)(sp + (size_t)(i >> 1) * (D_ * D_) + (i & 1) * (16 * D_));
            }

            // ---- compute step s from Bs[cur] ----
            const unsigned short* bsrc = Bs[cur];
            #pragma unroll
            for (int el = 0; el < 4; ++el) {
                f32x4 Ce[4][2];
                #pragma unroll
                for (int mi = 0; mi < 4; ++mi)
                    #pragma unroll
                    for (int ni = 0; ni < 2; ++ni)
                        Ce[mi][ni] = (f32x4){0.f, 0.f, 0.f, 0.f};
                #pragma unroll
                for (int ks = 0; ks < 2; ++ks) {
                    short8 Bf[2];
                    #pragma unroll
                    for (int ni = 0; ni < 2; ++ni)
                        Bf[ni] = *(const short8*)&bsrc[(el * 32 + ni * 16 + l16) * 72 + ks * 32 + quad * 8];
                    #pragma unroll
                    for (int mi = 0; mi < 4; ++mi)
                        #pragma unroll
                        for (int ni = 0; ni < 2; ++ni)
                            Ce[mi][ni] = __builtin_amdgcn_mfma_f32_16x16x32_bf16(
                                A[mi][ks], Bf[ni], Ce[mi][ni], 0, 0, 0);
                }
                // C/D layout: col = l16 (n), row = quad*4 + reg
                const float* wrow = ws[p * 4 + el];
                #pragma unroll
                for (int mi = 0; mi < 4; ++mi) {
                    const int rbase = m0 + mi * 16 + quad * 4;
                    float w0 = wrow[rbase + 0], w1 = wrow[rbase + 1];
                    float w2 = wrow[rbase + 2], w3 = wrow[rbase + 3];
                    #pragma unroll
                    for (int ni = 0; ni < 2; ++ni) {
                        Ct[mi][ni].x += w0 * Ce[mi][ni].x;
                        Ct[mi][ni].y += w1 * Ce[mi][ni].y;
                        Ct[mi][ni].z += w2 * Ce[mi][ni].z;
                        Ct[mi][ni].w += w3 * Ce[mi][ni].w;
                    }
                }
            }

            // ---- convert + write next step into Bs[cur^1] ----
            if (pre) {
                unsigned short* bdst = Bs[cur ^ 1];
                #pragma unroll
                for (int i = 0; i < 8; ++i) {
                    const int dr = (i >> 1) * 32 + (i & 1) * 16 + srow;
                    uint2 v2;
                    v2.x = cvt_pk_bf16(st[i].x, st[i].y);
                    v2.y = cvt_pk_bf16(st[i].z, st[i].w);
                    *(uint2*)&bdst[dr * 72 + scol] = v2;
                }
            }
            __syncthreads();   // writes visible; readers of Bs[cur] done
            cur ^= 1;
        }
    }

    #pragma unroll
    for (int mi = 0; mi < 4; ++mi)
        #pragma unroll
        for (int ni = 0; ni < 2; ++ni) {
            const int row = m0 + mi * 16 + quad * 4;
            const int col = n0 + ni * 16 + l16;
            if (TWO) {
                float* base = dst + ((size_t)g * B_ + row) * D_ + col;
                base[0 * D_] = Ct[mi][ni].x;
                base[1 * D_] = Ct[mi][ni].y;
                base[2 * D_] = Ct[mi][ni].z;
                base[3 * D_] = Ct[mi][ni].w;
            } else {
                unsafeAtomicAdd(&dst[(row + 0) * D_ + col], Ct[mi][ni].x);
                unsafeAtomicAdd(&dst[(row + 1) * D_ + col], Ct[mi][ni].y);
                unsafeAtomicAdd(&dst[(row + 2) * D_ + col], Ct[mi][ni].z);
                unsafeAtomicAdd(&dst[(row + 3) * D_ + col], Ct[mi][ni].w);
            }
        }
}

// ---------------- kernel 4: sum the NG partial copies -----------------------
template <int NG>
__global__ __launch_bounds__(256) void k_reduce(const float* __restrict__ P,
                                                float* __restrict__ out) {
    const int t = blockIdx.x * 256 + threadIdx.x;   // 0..32767 (float4 idx)
    const f32x4* p4 = (const f32x4*)P;
    f32x4 acc = (f32x4){0.f, 0.f, 0.f, 0.f};
    #pragma unroll 8
    for (int gidx = 0; gidx < NG; ++gidx) {
        f32x4 v = p4[(size_t)gidx * 32768 + t];
        acc.x += v.x; acc.y += v.y; acc.z += v.z; acc.w += v.w;
    }
    ((f32x4*)out)[t] = acc;
}

extern "C" void kernel_launch(void* const* d_in, const int* in_sizes, int n_in,
                              void* d_out, int out_size, void* d_ws, size_t ws_size,
                              hipStream_t stream) {
    const float* x     = (const float*)d_in[0];
    const float* gw    = (const float*)d_in[1];
    const float* gb    = (const float*)d_in[2];
    const float* tiles = (const float*)d_in[3];
    float* out = (float*)d_out;

    // ws layout: xb bf16 (256 KB) | wT f32 (512 KB) | { logits f64 (1 MB) / P }
    // P aliases logits: logits are dead once k_topk finishes.
    char* base = (char*)d_ws;
    unsigned short* xb  = (unsigned short*)base;
    float* wT           = (float*)(base + 262144);
    double* logits      = (double*)(base + 262144 + 524288);
    float* P            = (float*)(base + 262144 + 524288);
    const size_t fixed  = 262144 + 524288;                       // xb + wT
    const size_t slot   = (size_t)B_ * D_ * sizeof(float);       // 512 KB
    const size_t need16 = fixed + 32 * slot;                     // ~16.75 MiB
    const size_t need32 = fixed + 16 * slot;                     // ~8.75 MiB

    k_gate<<<dim3(32, 8), 512, 0, stream>>>(x, gw, logits);
    k_topk<<<256, 512, 0, stream>>>(logits, gb, x, wT, xb);
    if (ws_size >= need16) {
        k_moe<16, true><<<512, 256, 0, stream>>>(xb, wT, tiles, P);
        k_reduce<32><<<128, 256, 0, stream>>>(P, out);
    } else if (ws_size >= need32) {
        k_moe<32, true><<<256, 256, 0, stream>>>(xb, wT, tiles, P);
        k_reduce<16><<<128, 256, 0, stream>>>(P, out);
    } else {
        hipMemsetAsync(out, 0, (size_t)out_size * sizeof(float), stream);
        k_moe<8, false><<<1024, 256, 0, stream>>>(xb, wT, tiles, out);
    }
}

// Round 4
// 749.844 us; speedup vs baseline: 2.0652x; 1.4704x over previous
//
#include <hip/hip_runtime.h>
#include <hip/hip_bf16.h>

#define B_ 256
#define D_ 512
#define E_ 512
#define K_ 154

typedef __attribute__((ext_vector_type(8))) short short8;
typedef __attribute__((ext_vector_type(4))) float f32x4;

#define AS1 __attribute__((address_space(1)))
#define AS3 __attribute__((address_space(3)))

__device__ __forceinline__ unsigned short f2bf(float f) {
    unsigned u = __float_as_uint(f);
    u = (u + 0x7fffu + ((u >> 16) & 1u)) >> 16;
    return (unsigned short)u;
}

// RNE pack of two f32 -> one u32 of 2x bf16 (low = a, high = b). Same bits
// as f2bf (both RNE); single VALU op.
__device__ __forceinline__ unsigned cvt_pk_bf16(float a, float b) {
    unsigned r;
    asm("v_cvt_pk_bf16_f32 %0, %1, %2" : "=v"(r) : "v"(a), "v"(b));
    return r;
}

__device__ __forceinline__ short8 pack_bf16x8(f32x4 a, f32x4 b) {
    union { unsigned u[4]; short8 s; } r;
    r.u[0] = cvt_pk_bf16(a.x, a.y);
    r.u[1] = cvt_pk_bf16(a.z, a.w);
    r.u[2] = cvt_pk_bf16(b.x, b.y);
    r.u[3] = cvt_pk_bf16(b.z, b.w);
    return r.s;
}

// ---------------- kernel 1: gate logits, fp64, LDS-tiled & coalesced -------
__global__ __launch_bounds__(512) void k_gate(const float* __restrict__ x,
                                              const float* __restrict__ gw,
                                              double* __restrict__ logits) {
    const int tg = blockIdx.x;   // 0..31 : 8 tokens
    const int eg = blockIdx.y;   // 0..7  : 64 experts
    const int tid = threadIdx.x;
    const int t0 = tg * 8, e0 = eg * 64;
    __shared__ double xs[8][512];     // 32 KB
    __shared__ float gws[64][65];     // 16.6 KB, +1 pad
    #pragma unroll
    for (int i = 0; i < 8; ++i) {
        int j = i * 512 + tid;
        xs[j >> 9][j & 511] = (double)x[(t0 + (j >> 9)) * D_ + (j & 511)];
    }
    const int e = tid & 63, tl = tid >> 6;
    double acc = 0.0;
    for (int dc = 0; dc < 8; ++dc) {
        __syncthreads();
        #pragma unroll
        for (int i = 0; i < 8; ++i) {
            int j = i * 512 + tid;
            gws[j >> 6][j & 63] = gw[(e0 + (j >> 6)) * D_ + dc * 64 + (j & 63)];
        }
        __syncthreads();
        #pragma unroll 8
        for (int d = 0; d < 64; ++d)
            acc = fma((double)gws[e][d], xs[tl][dc * 64 + d], acc);
    }
    logits[(t0 + tl) * E_ + e0 + e] = acc;
}

// ---------------- kernel 2: exact top-k (rank) + fp64 softmax + x->bf16 ----
__global__ __launch_bounds__(512) void k_topk(const double* __restrict__ logits,
                                              const float* __restrict__ gb,
                                              const float* __restrict__ x,
                                              float* __restrict__ wT,
                                              unsigned short* __restrict__ xb) {
    const int b = blockIdx.x;
    const int e = threadIdx.x;
    __shared__ double vals[E_];
    __shared__ double red[512];
    double v = logits[b * E_ + e] + (double)gb[e];
    vals[e] = v;
    xb[b * D_ + e] = f2bf(x[b * D_ + e]);   // D_ == E_ == 512
    __syncthreads();
    int cnt = 0;
    double m = -1.0e300;
    for (int j = 0; j < E_; ++j) {
        double vj = vals[j];
        m = fmax(m, vj);
        cnt += (vj > v || (vj == v && j < e)) ? 1 : 0;
    }
    double p = (cnt < K_) ? exp(v - m) : 0.0;
    red[e] = p;
    __syncthreads();
    for (int s = 256; s > 0; s >>= 1) {
        if (e < s) red[e] += red[e + s];
        __syncthreads();
    }
    wT[e * B_ + b] = (float)(p / red[0]);
}

// ---------------- kernel 3: main contraction, glds fragment-linear ---------
// grid = 16 n-tiles(32) x (512/EPG) expert-groups; block 256 (4 waves).
// v5: global_load_lds (zero data VGPRs, 1 KB in flight per instr) into a
// FRAGMENT-IDENTICAL LDS layout: DMA instr (ks,ni,h) pulls, per lane, the
// exact 16B that lane's MFMA B-fragment needs. DMA writes base+lane*16, so
// compute reads ds_read_b128 at frag_base+lane*16: stride-16B, conflict-
// free, no swizzle (kills v3's per-lane addr-math spill: ONE per-lane base
// + wave-uniform delta per call), no staged-data regs (kills v4's st spill).
// Double-buffered, T14 order: issue step s+1's 8 DMAs, compute step s, one
// barrier/step (drain lands after ~600cyc of compute; 2 blocks/CU stagger).
// Arch VGPR budget: Ct 32 + A 32 + Ce 16 (ni-split) + u,v 8 + misc ~25 ->
// fits the 128-reg split of (256,2). v3/v4 post-mortems: WRITE_SIZE is the
// spill detector (698MB-1.7GB scratch); predict ~20 MB here.
template <int EPG, bool TWO>
__global__ __launch_bounds__(256, 2) void k_moe(const unsigned short* __restrict__ xb,
                                                const float* __restrict__ wT,
                                                const float* __restrict__ tiles,
                                                float* __restrict__ dst) {
    const int nt = blockIdx.x & 15;
    const int g  = blockIdx.x >> 4;
    const int n0 = nt * 32;
    const int e0 = g * EPG;
    const int tid  = threadIdx.x;
    const int wv   = tid >> 6;
    const int lane = tid & 63;
    const int m0   = wv * 64;
    const int quad = lane >> 4;
    const int l16  = lane & 15;
    constexpr int PSTEPS = EPG / 4;
    constexpr int NSTEP  = 8 * PSTEPS;

    // [buf][expert-slot][ks][ni][h][256 floats = 64 lanes x 4]  = 64 KB
    __shared__ __align__(16) float Bs[2][4][2][2][2][256];
    __shared__ float ws[EPG][B_];                                // EPG KB

    #pragma unroll
    for (int i = 0; i < EPG; ++i) {
        int idx = i * 256 + tid;
        ws[idx >> 8][idx & 255] = wT[(e0 + (idx >> 8)) * B_ + (idx & 255)];
    }

    // per-lane source base: row (n0+l16), k-octet quad*8. Everything else
    // (expert, ni, kc, ks, h) is a wave-uniform delta.
    const float* pbase = tiles + (size_t)(n0 + l16) * D_ + quad * 8;

    auto stage = [&](int buf, int step) {
        const int kc = step / PSTEPS, p = step & (PSTEPS - 1);
        const size_t ebase = (size_t)(e0 + p * 4 + wv) * (D_ * D_) + kc * 64;
        #pragma unroll
        for (int ks = 0; ks < 2; ++ks)
            #pragma unroll
            for (int ni = 0; ni < 2; ++ni)
                #pragma unroll
                for (int h = 0; h < 2; ++h) {
                    const float* src = pbase + ebase + ni * (16 * D_) + ks * 32 + h * 4;
                    __builtin_amdgcn_global_load_lds((const AS1 void*)src,
                                                     (AS3 void*)&Bs[buf][wv][ks][ni][h][0],
                                                     16, 0, 0);
                }
    };

    f32x4 Ct[4][2];
    #pragma unroll
    for (int mi = 0; mi < 4; ++mi)
        #pragma unroll
        for (int ni = 0; ni < 2; ++ni)
            Ct[mi][ni] = (f32x4){0.f, 0.f, 0.f, 0.f};

    stage(0, 0);
    __syncthreads();   // drains prologue DMA (vmcnt 0) + covers ws
    int cur = 0;

    const int lofs = lane * 4;   // float offset of this lane's 16B in a block

    for (int kc = 0; kc < 8; ++kc) {
        const int k0 = kc * 64;
        // A fragments from xb (bf16, L2-resident): once per kc
        short8 A[4][2];
        #pragma unroll
        for (int mi = 0; mi < 4; ++mi)
            #pragma unroll
            for (int ks = 0; ks < 2; ++ks)
                A[mi][ks] = *(const short8*)&xb[(m0 + mi * 16 + l16) * D_ + k0 + ks * 32 + quad * 8];

        #pragma unroll 1
        for (int p = 0; p < PSTEPS; ++p) {
            const int s = kc * PSTEPS + p;
            if (s + 1 < NSTEP) stage(cur ^ 1, s + 1);   // 8 KB/wave in flight

            #pragma unroll
            for (int el = 0; el < 4; ++el) {
                const float* wrow = ws[p * 4 + el];
                #pragma unroll
                for (int ni = 0; ni < 2; ++ni) {
                    f32x4 Ce[4];
                    #pragma unroll
                    for (int mi = 0; mi < 4; ++mi)
                        Ce[mi] = (f32x4){0.f, 0.f, 0.f, 0.f};
                    #pragma unroll
                    for (int ks = 0; ks < 2; ++ks) {
                        f32x4 u = *(const f32x4*)&Bs[cur][el][ks][ni][0][lofs];
                        f32x4 v = *(const f32x4*)&Bs[cur][el][ks][ni][1][lofs];
                        short8 Bf = pack_bf16x8(u, v);
                        #pragma unroll
                        for (int mi = 0; mi < 4; ++mi)
                            Ce[mi] = __builtin_amdgcn_mfma_f32_16x16x32_bf16(
                                A[mi][ks], Bf, Ce[mi], 0, 0, 0);
                    }
                    // C/D layout: col = l16 (n), row = quad*4 + reg
                    #pragma unroll
                    for (int mi = 0; mi < 4; ++mi) {
                        const int rb = m0 + mi * 16 + quad * 4;
                        Ct[mi][ni].x += wrow[rb + 0] * Ce[mi].x;
                        Ct[mi][ni].y += wrow[rb + 1] * Ce[mi].y;
                        Ct[mi][ni].z += wrow[rb + 2] * Ce[mi].z;
                        Ct[mi][ni].w += wrow[rb + 3] * Ce[mi].w;
                    }
                }
            }
            __syncthreads();   // DMA for s+1 done; readers of cur done
            cur ^= 1;
        }
    }

    #pragma unroll
    for (int mi = 0; mi < 4; ++mi)
        #pragma unroll
        for (int ni = 0; ni < 2; ++ni) {
            const int row = m0 + mi * 16 + quad * 4;
            const int col = n0 + ni * 16 + l16;
            if (TWO) {
                float* base = dst + ((size_t)g * B_ + row) * D_ + col;
                base[0 * D_] = Ct[mi][ni].x;
                base[1 * D_] = Ct[mi][ni].y;
                base[2 * D_] = Ct[mi][ni].z;
                base[3 * D_] = Ct[mi][ni].w;
            } else {
                unsafeAtomicAdd(&dst[(row + 0) * D_ + col], Ct[mi][ni].x);
                unsafeAtomicAdd(&dst[(row + 1) * D_ + col], Ct[mi][ni].y);
                unsafeAtomicAdd(&dst[(row + 2) * D_ + col], Ct[mi][ni].z);
                unsafeAtomicAdd(&dst[(row + 3) * D_ + col], Ct[mi][ni].w);
            }
        }
}

// ---------------- kernel 4: sum the NG partial copies -----------------------
template <int NG>
__global__ __launch_bounds__(256) void k_reduce(const float* __restrict__ P,
                                                float* __restrict__ out) {
    const int t = blockIdx.x * 256 + threadIdx.x;   // 0..32767 (float4 idx)
    const f32x4* p4 = (const f32x4*)P;
    f32x4 acc = (f32x4){0.f, 0.f, 0.f, 0.f};
    #pragma unroll 8
    for (int gidx = 0; gidx < NG; ++gidx) {
        f32x4 v = p4[(size_t)gidx * 32768 + t];
        acc.x += v.x; acc.y += v.y; acc.z += v.z; acc.w += v.w;
    }
    ((f32x4*)out)[t] = acc;
}

extern "C" void kernel_launch(void* const* d_in, const int* in_sizes, int n_in,
                              void* d_out, int out_size, void* d_ws, size_t ws_size,
                              hipStream_t stream) {
    const float* x     = (const float*)d_in[0];
    const float* gw    = (const float*)d_in[1];
    const float* gb    = (const float*)d_in[2];
    const float* tiles = (const float*)d_in[3];
    float* out = (float*)d_out;

    // ws layout: xb bf16 (256 KB) | wT f32 (512 KB) | { logits f64 (1 MB) / P }
    // P aliases logits: logits are dead once k_topk finishes.
    char* base = (char*)d_ws;
    unsigned short* xb  = (unsigned short*)base;
    float* wT           = (float*)(base + 262144);
    double* logits      = (double*)(base + 262144 + 524288);
    float* P            = (float*)(base + 262144 + 524288);
    const size_t fixed  = 262144 + 524288;                       // xb + wT
    const size_t slot   = (size_t)B_ * D_ * sizeof(float);       // 512 KB
    const size_t need16 = fixed + 32 * slot;                     // ~16.75 MiB
    const size_t need32 = fixed + 16 * slot;                     // ~8.75 MiB

    k_gate<<<dim3(32, 8), 512, 0, stream>>>(x, gw, logits);
    k_topk<<<256, 512, 0, stream>>>(logits, gb, x, wT, xb);
    if (ws_size >= need16) {
        k_moe<16, true><<<512, 256, 0, stream>>>(xb, wT, tiles, P);
        k_reduce<32><<<128, 256, 0, stream>>>(P, out);
    } else if (ws_size >= need32) {
        k_moe<32, true><<<256, 256, 0, stream>>>(xb, wT, tiles, P);
        k_reduce<16><<<128, 256, 0, stream>>>(P, out);
    } else {
        hipMemsetAsync(out, 0, (size_t)out_size * sizeof(float), stream);
        k_moe<8, false><<<1024, 256, 0, stream>>>(xb, wT, tiles, out);
    }
}